// Round 1
// baseline (1713.046 us; speedup 1.0000x reference)
//
#include <hip/hip_runtime.h>
#include <cstdint>

// Problem constants
#define Bb 4
#define Tt 4096
#define Cc 2048
#define Hh 16
#define Dh 128
#define BT (Bb * Tt)            // 16384 rows
#define NCHUNK 32
#define TCHUNK 128              // NCHUNK*TCHUNK == Tt
#define NCHAN (Bb * Cc)         // 8192 scan channels

typedef __bf16 bf16x8 __attribute__((ext_vector_type(8)));
typedef float f32x4 __attribute__((ext_vector_type(4)));
typedef unsigned short u16x8 __attribute__((ext_vector_type(8)));

__device__ __forceinline__ float bf2f(unsigned short u) {
  return __uint_as_float(((unsigned)u) << 16);
}
__device__ __forceinline__ unsigned short f2bf(float f) {
  unsigned u = __float_as_uint(f);
  u = u + 0x7fffu + ((u >> 16) & 1u);   // RNE
  return (unsigned short)(u >> 16);
}

// async global->LDS, 16B per lane; lds must be wave-uniform (HW writes base + lane*16)
__device__ __forceinline__ void async_copy16(void* lds, const void* gmem) {
  auto* lp = (__attribute__((address_space(3))) unsigned int*)(unsigned)(uintptr_t)(lds);
  auto* gp = (const __attribute__((address_space(1))) unsigned int*)(uintptr_t)(gmem);
  __builtin_amdgcn_global_load_lds(gp, lp, 16, 0, 0);
}

// ---------------- fp32 -> bf16 convert ----------------
__global__ __launch_bounds__(256) void cvt_kernel(const float* __restrict__ in,
                                                  unsigned short* __restrict__ out, int n) {
  int i = (blockIdx.x * 256 + threadIdx.x) * 4;
  if (i + 3 < n) {
    float4 v = *(const float4*)(in + i);
    unsigned r0 = (unsigned)f2bf(v.x) | ((unsigned)f2bf(v.y) << 16);
    unsigned r1 = (unsigned)f2bf(v.z) | ((unsigned)f2bf(v.w) << 16);
    *(uint2*)(out + i) = make_uint2(r0, r1);
  }
}

// ---------------- depthwise causal conv K=4 + SiLU + x->bf16 ----------------
__global__ __launch_bounds__(256) void conv_kernel(const float* __restrict__ x,
                                                   const float* __restrict__ cw,
                                                   const float* __restrict__ cb,
                                                   unsigned short* __restrict__ xb,
                                                   unsigned short* __restrict__ xcb) {
  size_t idx4 = ((size_t)blockIdx.x * 256 + threadIdx.x) * 4;
  int c = (int)(idx4 & (Cc - 1));
  size_t bt = idx4 >> 11;
  int t = (int)(bt & (Tt - 1));
  float4 xc = *(const float4*)(x + idx4);
  float v0[4] = {xc.x, xc.y, xc.z, xc.w};
  // write x as bf16
  unsigned p0 = (unsigned)f2bf(v0[0]) | ((unsigned)f2bf(v0[1]) << 16);
  unsigned p1 = (unsigned)f2bf(v0[2]) | ((unsigned)f2bf(v0[3]) << 16);
  *(uint2*)(xb + idx4) = make_uint2(p0, p1);
  float a[4];
#pragma unroll
  for (int u = 0; u < 4; u++) a[u] = cb[c + u] + cw[(c + u) * 4 + 3] * v0[u];
#pragma unroll
  for (int j = 1; j <= 3; j++) {
    if (t >= j) {
      float4 xp = *(const float4*)(x + idx4 - (size_t)j * Cc);
      float vp[4] = {xp.x, xp.y, xp.z, xp.w};
#pragma unroll
      for (int u = 0; u < 4; u++) a[u] += cw[(c + u) * 4 + 3 - j] * vp[u];
    }
  }
  unsigned short o[4];
#pragma unroll
  for (int u = 0; u < 4; u++) {
    float s = a[u];
    float sig = 1.f / (1.f + expf(-s));
    o[u] = f2bf(s * sig);
  }
  unsigned q0 = (unsigned)o[0] | ((unsigned)o[1] << 16);
  unsigned q1 = (unsigned)o[2] | ((unsigned)o[3] << 16);
  *(uint2*)(xcb + idx4) = make_uint2(q0, q1);
}

// ---------------- bf16 GEMM: C[M,N] = A[M,K] * B[N,K]^T ----------------
// EPI: 0 = bf16 store, 1 = sigmoid(acc + bias[col]) bf16 store, 2 = fp32 store
template <int EPI>
__global__ __launch_bounds__(256) void gemm_bt(const unsigned short* __restrict__ A,
                                               const unsigned short* __restrict__ B,
                                               void* __restrict__ C,
                                               const float* __restrict__ bias,
                                               int M, int N, int K) {
  __shared__ unsigned short As[128 * 32];
  __shared__ unsigned short Bs[128 * 32];
  const int tid = threadIdx.x;
  const int wave = tid >> 6;
  const int lane = tid & 63;
  const int m0 = blockIdx.x * 128;
  const int n0 = blockIdx.y * 128;
  const int wm = (wave & 1) * 64;
  const int wn = (wave >> 1) * 64;

  // staging map: issue e covers rows e*64 + wave*16 + lane/4, cols (lane%4)*8
  const int srow = wave * 16 + (lane >> 2);
  const int scol = (lane & 3) * 8;
  const unsigned short* Ag0 = A + (size_t)(m0 + srow) * K + scol;
  const unsigned short* Ag1 = A + (size_t)(m0 + 64 + srow) * K + scol;
  const unsigned short* Bg0 = B + (size_t)(n0 + srow) * K + scol;
  const unsigned short* Bg1 = B + (size_t)(n0 + 64 + srow) * K + scol;
  unsigned short* As0 = &As[wave * 512];
  unsigned short* As1 = &As[2048 + wave * 512];
  unsigned short* Bs0 = &Bs[wave * 512];
  unsigned short* Bs1 = &Bs[2048 + wave * 512];

  f32x4 acc[4][4] = {};
  const int frow = lane & 15;
  const int fcol = (lane >> 4) * 8;

  for (int k0 = 0; k0 < K; k0 += 32) {
    async_copy16(As0, Ag0 + k0);
    async_copy16(As1, Ag1 + k0);
    async_copy16(Bs0, Bg0 + k0);
    async_copy16(Bs1, Bg1 + k0);
    __builtin_amdgcn_s_waitcnt(0);
    __syncthreads();
    bf16x8 af[4], bff[4];
#pragma unroll
    for (int i = 0; i < 4; i++) {
      af[i]  = __builtin_bit_cast(bf16x8, *(const u16x8*)&As[(wm + i * 16 + frow) * 32 + fcol]);
      bff[i] = __builtin_bit_cast(bf16x8, *(const u16x8*)&Bs[(wn + i * 16 + frow) * 32 + fcol]);
    }
#pragma unroll
    for (int i = 0; i < 4; i++)
#pragma unroll
      for (int j = 0; j < 4; j++)
        acc[i][j] = __builtin_amdgcn_mfma_f32_16x16x32_bf16(af[i], bff[j], acc[i][j], 0, 0, 0);
    __syncthreads();
  }

  const int crow0 = (lane >> 4) * 4;
  const int ccol = lane & 15;
#pragma unroll
  for (int i = 0; i < 4; i++) {
#pragma unroll
    for (int j = 0; j < 4; j++) {
      int col = n0 + wn + j * 16 + ccol;
      float bv = (EPI == 1) ? bias[col] : 0.f;
#pragma unroll
      for (int r = 0; r < 4; r++) {
        int row = m0 + wm + i * 16 + crow0 + r;
        float v = acc[i][j][r];
        if (EPI == 1) v = 1.f / (1.f + expf(-(v + bv)));
        if (EPI == 2)
          ((float*)C)[(size_t)row * N + col] = v;
        else
          ((unsigned short*)C)[(size_t)row * N + col] = f2bf(v);
      }
    }
  }
}

// ---------------- l2 normalize rows of 128 (bf16, in-place) ----------------
__global__ __launch_bounds__(256) void l2norm_kernel(unsigned short* __restrict__ t) {
  size_t row = ((size_t)blockIdx.x * 4) + (threadIdx.x >> 6);
  int lane = threadIdx.x & 63;
  unsigned* p = (unsigned*)(t + row * 128);
  unsigned u = p[lane];
  float a = bf2f((unsigned short)(u & 0xffff));
  float b = bf2f((unsigned short)(u >> 16));
  float sq = a * a + b * b;
#pragma unroll
  for (int o = 32; o > 0; o >>= 1) sq += __shfl_down(sq, o);
  sq = __shfl(sq, 0);
  float inv = 1.0f / fmaxf(sqrtf(sq), 1e-12f);
  a *= inv; b *= inv;
  p[lane] = (unsigned)f2bf(a) | ((unsigned)f2bf(b) << 16);
}

// ---------------- chunked decayed scan ----------------
// phase 1: per-(channel,chunk) local end value L
__global__ __launch_bounds__(256) void scan_p1(const unsigned short* __restrict__ kb,
                                               const unsigned short* __restrict__ vb,
                                               const float* __restrict__ gamma,
                                               float* __restrict__ carry) {
  int idx = blockIdx.x * 256 + threadIdx.x;     // [0, NCHUNK*NCHAN)
  int ch = idx & (NCHAN - 1);
  int chunk = idx >> 13;
  int b = ch >> 11, c = ch & (Cc - 1), h = c >> 7;
  float g = gamma[h];
  size_t base = ((size_t)b * Tt + (size_t)chunk * TCHUNK) * Cc + c;
  float L = 0.f;
#pragma unroll 8
  for (int t = 0; t < TCHUNK; t++) {
    size_t a = base + (size_t)t * Cc;
    L = g * L + bf2f(kb[a]) * bf2f(vb[a]);
  }
  carry[(size_t)chunk * NCHAN + ch] = L;
}

// phase 2: serial combine across chunks per channel; carry[] becomes carry-IN per chunk
__global__ __launch_bounds__(256) void scan_p2(float* __restrict__ carry,
                                               const float* __restrict__ gamma) {
  int ch = blockIdx.x * 256 + threadIdx.x;      // [0, NCHAN)
  int h = (ch & (Cc - 1)) >> 7;
  float g = gamma[h];
  float gTc = g;
#pragma unroll
  for (int i = 0; i < 7; i++) gTc *= gTc;       // g^128
  float E = 0.f;
  for (int cidx = 0; cidx < NCHUNK; cidx++) {
    float L = carry[(size_t)cidx * NCHAN + ch];
    carry[(size_t)cidx * NCHAN + ch] = E;
    E = gTc * E + L;
  }
}

// phase 3: recompute with carry-in, emit out = gate * S * q (bf16, in-place over gate buffer)
__global__ __launch_bounds__(256) void scan_p3(const unsigned short* __restrict__ kb,
                                               const unsigned short* __restrict__ vb,
                                               const unsigned short* __restrict__ qb,
                                               unsigned short* __restrict__ gb,
                                               const float* __restrict__ gamma,
                                               const float* __restrict__ carry) {
  int idx = blockIdx.x * 256 + threadIdx.x;
  int ch = idx & (NCHAN - 1);
  int chunk = idx >> 13;
  int b = ch >> 11, c = ch & (Cc - 1), h = c >> 7;
  float g = gamma[h];
  float S = carry[(size_t)chunk * NCHAN + ch];
  size_t base = ((size_t)b * Tt + (size_t)chunk * TCHUNK) * Cc + c;
#pragma unroll 4
  for (int t = 0; t < TCHUNK; t++) {
    size_t a = base + (size_t)t * Cc;
    S = g * S + bf2f(kb[a]) * bf2f(vb[a]);
    float o = bf2f(gb[a]) * S * bf2f(qb[a]);
    gb[a] = f2bf(o);
  }
}

// ---------------- LayerNorm over C=2048, in-place on fp32 ----------------
__global__ __launch_bounds__(256) void ln_kernel(float* __restrict__ y,
                                                 const float* __restrict__ w,
                                                 const float* __restrict__ b) {
  float* p = y + (size_t)blockIdx.x * Cc;
  int tid = threadIdx.x;
  float v[8];
  float s = 0.f, sq = 0.f;
#pragma unroll
  for (int i = 0; i < 8; i++) {
    v[i] = p[tid + i * 256];
    s += v[i];
    sq += v[i] * v[i];
  }
#pragma unroll
  for (int o = 32; o > 0; o >>= 1) { s += __shfl_down(s, o); sq += __shfl_down(sq, o); }
  __shared__ float ss[4], ssq[4];
  int wave = tid >> 6, lane = tid & 63;
  if (lane == 0) { ss[wave] = s; ssq[wave] = sq; }
  __syncthreads();
  s = ss[0] + ss[1] + ss[2] + ss[3];
  sq = ssq[0] + ssq[1] + ssq[2] + ssq[3];
  float mu = s * (1.f / (float)Cc);
  float var = fmaxf(sq * (1.f / (float)Cc) - mu * mu, 0.f);
  float rs = rsqrtf(var + 1e-5f);
#pragma unroll
  for (int i = 0; i < 8; i++) {
    int c = tid + i * 256;
    p[c] = (v[i] - mu) * rs * w[c] + b[c];
  }
}

extern "C" void kernel_launch(void* const* d_in, const int* in_sizes, int n_in,
                              void* d_out, int out_size, void* d_ws, size_t ws_size,
                              hipStream_t stream) {
  const float* x      = (const float*)d_in[0];
  const float* Wq     = (const float*)d_in[1];
  const float* Wk     = (const float*)d_in[2];
  const float* Wv     = (const float*)d_in[3];
  const float* Wo     = (const float*)d_in[4];
  const float* conv_w = (const float*)d_in[5];
  const float* conv_b = (const float*)d_in[6];
  const float* gate_w = (const float*)d_in[7];
  const float* gate_b = (const float*)d_in[8];
  const float* ln_w   = (const float*)d_in[9];
  const float* ln_b   = (const float*)d_in[10];
  const float* gamma  = (const float*)d_in[11];

  char* ws = (char*)d_ws;
  const size_t SZ_BTC_BF16 = (size_t)BT * Cc * 2;   // 67108864
  const size_t SZ_W_BF16   = (size_t)Cc * Cc * 2;   // 8388608
  unsigned short* xb  = (unsigned short*)(ws);
  unsigned short* xcb = (unsigned short*)(ws + SZ_BTC_BF16);
  unsigned short* wqb = (unsigned short*)(ws + 2 * SZ_BTC_BF16);
  unsigned short* wkb = (unsigned short*)(ws + 2 * SZ_BTC_BF16 + SZ_W_BF16);
  unsigned short* wvb = (unsigned short*)(ws + 2 * SZ_BTC_BF16 + 2 * SZ_W_BF16);
  unsigned short* wob = (unsigned short*)(ws + 2 * SZ_BTC_BF16 + 3 * SZ_W_BF16);
  unsigned short* wgb = (unsigned short*)(ws + 2 * SZ_BTC_BF16 + 4 * SZ_W_BF16);
  char* p2 = ws + 2 * SZ_BTC_BF16 + 5 * SZ_W_BF16;
  unsigned short* qb = (unsigned short*)(p2);
  unsigned short* kb = (unsigned short*)(p2 + SZ_BTC_BF16);
  unsigned short* vb = (unsigned short*)(p2 + 2 * SZ_BTC_BF16);
  unsigned short* gb = (unsigned short*)(p2 + 3 * SZ_BTC_BF16);  // gate, then reused as `out`
  float* carry       = (float*)(p2 + 4 * SZ_BTC_BF16);           // 32*8192*4 = 1 MB

  const int nW = Cc * Cc;
  // weight converts
  cvt_kernel<<<nW / 1024, 256, 0, stream>>>(Wq, wqb, nW);
  cvt_kernel<<<nW / 1024, 256, 0, stream>>>(Wk, wkb, nW);
  cvt_kernel<<<nW / 1024, 256, 0, stream>>>(Wv, wvb, nW);
  cvt_kernel<<<nW / 1024, 256, 0, stream>>>(Wo, wob, nW);
  cvt_kernel<<<nW / 1024, 256, 0, stream>>>(gate_w, wgb, nW);
  // conv + x cast
  conv_kernel<<<(BT * Cc) / 1024, 256, 0, stream>>>(x, conv_w, conv_b, xb, xcb);

  dim3 ggrid(BT / 128, Cc / 128);
  gemm_bt<0><<<ggrid, 256, 0, stream>>>(xb, wqb, qb, nullptr, BT, Cc, Cc);
  gemm_bt<0><<<ggrid, 256, 0, stream>>>(xb, wkb, kb, nullptr, BT, Cc, Cc);
  gemm_bt<0><<<ggrid, 256, 0, stream>>>(xb, wvb, vb, nullptr, BT, Cc, Cc);
  gemm_bt<1><<<ggrid, 256, 0, stream>>>(xcb, wgb, gb, gate_b, BT, Cc, Cc);

  // l2 normalize q, k over Dh=128
  l2norm_kernel<<<(BT * Hh) / 4, 256, 0, stream>>>(qb);
  l2norm_kernel<<<(BT * Hh) / 4, 256, 0, stream>>>(kb);

  // decayed scan + gating (out written in-place over gb)
  scan_p1<<<(NCHUNK * NCHAN) / 256, 256, 0, stream>>>(kb, vb, gamma, carry);
  scan_p2<<<NCHAN / 256, 256, 0, stream>>>(carry, gamma);
  scan_p3<<<(NCHUNK * NCHAN) / 256, 256, 0, stream>>>(kb, vb, qb, gb, gamma, carry);

  // y = out @ Wo^T  (fp32 into d_out), then LayerNorm in place
  gemm_bt<2><<<ggrid, 256, 0, stream>>>(gb, wob, d_out, nullptr, BT, Cc, Cc);
  ln_kernel<<<BT, 256, 0, stream>>>((float*)d_out, ln_w, ln_b);
}

// Round 2
// 1447.736 us; speedup vs baseline: 1.1833x; 1.1833x over previous
//
#include <hip/hip_runtime.h>
#include <cstdint>

// Problem constants
#define Bb 4
#define Tt 4096
#define Cc 2048
#define Hh 16
#define Dh 128
#define BT (Bb * Tt)            // 16384 rows
#define NCHUNK 32
#define TCHUNK 128              // NCHUNK*TCHUNK == Tt
#define NCHAN (Bb * Cc)         // 8192 scan channels
#define NQKV 6144               // 3*Cc

typedef __bf16 bf16x8 __attribute__((ext_vector_type(8)));
typedef float f32x4 __attribute__((ext_vector_type(4)));
typedef unsigned short u16x8 __attribute__((ext_vector_type(8)));

__device__ __forceinline__ float bf2f(unsigned short u) {
  return __uint_as_float(((unsigned)u) << 16);
}
__device__ __forceinline__ unsigned short f2bf(float f) {
  unsigned u = __float_as_uint(f);
  u = u + 0x7fffu + ((u >> 16) & 1u);   // RNE
  return (unsigned short)(u >> 16);
}

// async global->LDS, 16B per lane; lds must be wave-uniform (HW writes base + lane*16)
__device__ __forceinline__ void async_copy16(void* lds, const void* gmem) {
  auto* lp = (__attribute__((address_space(3))) unsigned int*)(unsigned)(uintptr_t)(lds);
  auto* gp = (const __attribute__((address_space(1))) unsigned int*)(uintptr_t)(gmem);
  __builtin_amdgcn_global_load_lds(gp, lp, 16, 0, 0);
}

// ---------------- fp32 -> bf16 convert: 5 weight matrices into one packed buffer ----
// dst layout: [wq | wk | wv | wo | wg], each nW = Cc*Cc elements
__global__ __launch_bounds__(256) void cvt5_kernel(const float* __restrict__ Wq,
                                                   const float* __restrict__ Wk,
                                                   const float* __restrict__ Wv,
                                                   const float* __restrict__ Wo,
                                                   const float* __restrict__ Wg,
                                                   unsigned short* __restrict__ dst) {
  size_t idx4 = ((size_t)blockIdx.x * 256 + threadIdx.x) * 4;
  int region = (int)(idx4 >> 22);               // nW = 2^22
  size_t off = idx4 & ((1u << 22) - 1);
  const float* src;
  switch (region) {
    case 0: src = Wq; break;
    case 1: src = Wk; break;
    case 2: src = Wv; break;
    case 3: src = Wo; break;
    default: src = Wg; break;
  }
  float4 v = *(const float4*)(src + off);
  unsigned r0 = (unsigned)f2bf(v.x) | ((unsigned)f2bf(v.y) << 16);
  unsigned r1 = (unsigned)f2bf(v.z) | ((unsigned)f2bf(v.w) << 16);
  *(uint2*)(dst + idx4) = make_uint2(r0, r1);
}

// ---------------- depthwise causal conv K=4 + SiLU + x->bf16 ----------------
// thread = 8 consecutive t x 4 channels; conv taps come from registers
__global__ __launch_bounds__(256) void conv_kernel(const float* __restrict__ x,
                                                   const float* __restrict__ cw,
                                                   const float* __restrict__ cb,
                                                   unsigned short* __restrict__ xb,
                                                   unsigned short* __restrict__ xcb) {
  int idx = blockIdx.x * 256 + threadIdx.x;
  int cg = idx & 511;                 // Cc/4
  int rg = idx >> 9;                  // row group over BT/8
  int c = cg * 4;
  size_t bt0 = (size_t)rg * 8;
  int t0 = (int)(bt0 & (Tt - 1));
  const float* xp = x + bt0 * Cc + c;

  float4 w4[4];
#pragma unroll
  for (int u = 0; u < 4; u++) w4[u] = *(const float4*)(cw + (size_t)(c + u) * 4);
  float4 bias = *(const float4*)(cb + c);
  const float* bs = (const float*)&bias;

  float xr[11][4];                    // rows t0-3..t0+7
  if (t0 != 0) {
#pragma unroll
    for (int j = 0; j < 3; j++) {
      float4 p = *(const float4*)(xp - (size_t)(3 - j) * Cc);
      xr[j][0] = p.x; xr[j][1] = p.y; xr[j][2] = p.z; xr[j][3] = p.w;
    }
  } else {
#pragma unroll
    for (int j = 0; j < 3; j++)
#pragma unroll
      for (int u = 0; u < 4; u++) xr[j][u] = 0.f;
  }
#pragma unroll
  for (int i = 0; i < 8; i++) {
    float4 p = *(const float4*)(xp + (size_t)i * Cc);
    xr[3 + i][0] = p.x; xr[3 + i][1] = p.y; xr[3 + i][2] = p.z; xr[3 + i][3] = p.w;
    // write x as bf16
    unsigned a0 = (unsigned)f2bf(p.x) | ((unsigned)f2bf(p.y) << 16);
    unsigned a1 = (unsigned)f2bf(p.z) | ((unsigned)f2bf(p.w) << 16);
    *(uint2*)(xb + (bt0 + i) * Cc + c) = make_uint2(a0, a1);
  }
#pragma unroll
  for (int i = 0; i < 8; i++) {
    unsigned short o[4];
#pragma unroll
    for (int u = 0; u < 4; u++) {
      const float* wf = (const float*)&w4[u];
      float a = bs[u];
#pragma unroll
      for (int j = 0; j < 4; j++) a += wf[3 - j] * xr[3 + i - j][u];
      float sig = 1.f / (1.f + expf(-a));
      o[u] = f2bf(a * sig);
    }
    unsigned q0 = (unsigned)o[0] | ((unsigned)o[1] << 16);
    unsigned q1 = (unsigned)o[2] | ((unsigned)o[3] << 16);
    *(uint2*)(xcb + (bt0 + i) * Cc + c) = make_uint2(q0, q1);
  }
}

// ---------------- bf16 GEMM: C[M,N] = A[M,K] * B[N,K]^T ----------------
// EPI: 1 = sigmoid(acc + bias[col]) bf16 store, 2 = fp32 store,
//      3 = fused qkv: bf16 store; rows l2-normalized over the 128-col tile when n0 < 2*Cc
template <int EPI>
__global__ __launch_bounds__(256) void gemm_bt(const unsigned short* __restrict__ A,
                                               const unsigned short* __restrict__ B,
                                               void* __restrict__ C,
                                               const float* __restrict__ bias,
                                               int M, int N, int K) {
  __shared__ unsigned short As[128 * 32];
  __shared__ unsigned short Bs[128 * 32];
  __shared__ float rowsq[128][2];
  const int tid = threadIdx.x;
  const int wave = tid >> 6;
  const int lane = tid & 63;
  const int m0 = blockIdx.x * 128;
  const int n0 = blockIdx.y * 128;
  const int wm = (wave & 1) * 64;
  const int wn = (wave >> 1) * 64;

  const int srow = wave * 16 + (lane >> 2);
  const int scol = (lane & 3) * 8;
  const unsigned short* Ag0 = A + (size_t)(m0 + srow) * K + scol;
  const unsigned short* Ag1 = A + (size_t)(m0 + 64 + srow) * K + scol;
  const unsigned short* Bg0 = B + (size_t)(n0 + srow) * K + scol;
  const unsigned short* Bg1 = B + (size_t)(n0 + 64 + srow) * K + scol;
  unsigned short* As0 = &As[wave * 512];
  unsigned short* As1 = &As[2048 + wave * 512];
  unsigned short* Bs0 = &Bs[wave * 512];
  unsigned short* Bs1 = &Bs[2048 + wave * 512];

  f32x4 acc[4][4] = {};
  const int frow = lane & 15;
  const int fcol = (lane >> 4) * 8;

  for (int k0 = 0; k0 < K; k0 += 32) {
    async_copy16(As0, Ag0 + k0);
    async_copy16(As1, Ag1 + k0);
    async_copy16(Bs0, Bg0 + k0);
    async_copy16(Bs1, Bg1 + k0);
    __builtin_amdgcn_s_waitcnt(0);
    __syncthreads();
    bf16x8 af[4], bff[4];
#pragma unroll
    for (int i = 0; i < 4; i++) {
      af[i]  = __builtin_bit_cast(bf16x8, *(const u16x8*)&As[(wm + i * 16 + frow) * 32 + fcol]);
      bff[i] = __builtin_bit_cast(bf16x8, *(const u16x8*)&Bs[(wn + i * 16 + frow) * 32 + fcol]);
    }
#pragma unroll
    for (int i = 0; i < 4; i++)
#pragma unroll
      for (int j = 0; j < 4; j++)
        acc[i][j] = __builtin_amdgcn_mfma_f32_16x16x32_bf16(af[i], bff[j], acc[i][j], 0, 0, 0);
    __syncthreads();
  }

  const int crow0 = (lane >> 4) * 4;
  const int ccol = lane & 15;

  float inv[4][4];
  bool donorm = (EPI == 3) && (n0 < 2 * Cc);
  if (donorm) {
#pragma unroll
    for (int i = 0; i < 4; i++) {
#pragma unroll
      for (int r = 0; r < 4; r++) {
        float sq = 0.f;
#pragma unroll
        for (int j = 0; j < 4; j++) { float v = acc[i][j][r]; sq += v * v; }
        sq += __shfl_xor(sq, 1);
        sq += __shfl_xor(sq, 2);
        sq += __shfl_xor(sq, 4);
        sq += __shfl_xor(sq, 8);
        if ((lane & 15) == 0) rowsq[wm + i * 16 + crow0 + r][wn >> 6] = sq;
      }
    }
    __syncthreads();
#pragma unroll
    for (int i = 0; i < 4; i++)
#pragma unroll
      for (int r = 0; r < 4; r++) {
        int rloc = wm + i * 16 + crow0 + r;
        float s = rowsq[rloc][0] + rowsq[rloc][1];
        inv[i][r] = 1.f / fmaxf(sqrtf(s), 1e-12f);
      }
  }

#pragma unroll
  for (int i = 0; i < 4; i++) {
#pragma unroll
    for (int j = 0; j < 4; j++) {
      int col = n0 + wn + j * 16 + ccol;
      float bv = (EPI == 1) ? bias[col] : 0.f;
#pragma unroll
      for (int r = 0; r < 4; r++) {
        int row = m0 + wm + i * 16 + crow0 + r;
        float v = acc[i][j][r];
        if (EPI == 1) v = 1.f / (1.f + expf(-(v + bv)));
        if (donorm) v *= inv[i][r];
        if (EPI == 2)
          ((float*)C)[(size_t)row * N + col] = v;
        else
          ((unsigned short*)C)[(size_t)row * N + col] = f2bf(v);
      }
    }
  }
}

// ---------------- chunked decayed scan (4 channels / thread) ----------------
// qkv layout: [BT, 6144] with q @0, k @2048, v @4096
__global__ __launch_bounds__(256) void scan_p1(const unsigned short* __restrict__ qkv,
                                               const float* __restrict__ gamma,
                                               float* __restrict__ carry) {
  int idx = blockIdx.x * 256 + threadIdx.x;     // [0, NCHUNK*NCHAN/4)
  int ch4 = idx & 2047;                         // NCHAN/4
  int chunk = idx >> 11;
  int b = ch4 >> 9;
  int c = (ch4 & 511) * 4;
  float g = gamma[c >> 7];
  const unsigned short* kb = qkv + ((size_t)(b * Tt + chunk * TCHUNK)) * NQKV + Cc + c;
  float L[4] = {0.f, 0.f, 0.f, 0.f};
#pragma unroll 4
  for (int t = 0; t < TCHUNK; t++) {
    const unsigned short* p = kb + (size_t)t * NQKV;
    uint2 kk = *(const uint2*)(p);
    uint2 vv = *(const uint2*)(p + Cc);
    L[0] = g * L[0] + bf2f((unsigned short)(kk.x & 0xffff)) * bf2f((unsigned short)(vv.x & 0xffff));
    L[1] = g * L[1] + bf2f((unsigned short)(kk.x >> 16))    * bf2f((unsigned short)(vv.x >> 16));
    L[2] = g * L[2] + bf2f((unsigned short)(kk.y & 0xffff)) * bf2f((unsigned short)(vv.y & 0xffff));
    L[3] = g * L[3] + bf2f((unsigned short)(kk.y >> 16))    * bf2f((unsigned short)(vv.y >> 16));
  }
  *(float4*)(carry + (size_t)chunk * NCHAN + b * Cc + c) = make_float4(L[0], L[1], L[2], L[3]);
}

__global__ __launch_bounds__(256) void scan_p2(float* __restrict__ carry,
                                               const float* __restrict__ gamma) {
  int ch = blockIdx.x * 256 + threadIdx.x;      // [0, NCHAN)
  int h = (ch & (Cc - 1)) >> 7;
  float g = gamma[h];
  float gTc = g;
#pragma unroll
  for (int i = 0; i < 7; i++) gTc *= gTc;       // g^128
  float E = 0.f;
  for (int cidx = 0; cidx < NCHUNK; cidx++) {
    float L = carry[(size_t)cidx * NCHAN + ch];
    carry[(size_t)cidx * NCHAN + ch] = E;
    E = gTc * E + L;
  }
}

__global__ __launch_bounds__(256) void scan_p3(const unsigned short* __restrict__ qkv,
                                               unsigned short* __restrict__ gb,
                                               const float* __restrict__ gamma,
                                               const float* __restrict__ carry) {
  int idx = blockIdx.x * 256 + threadIdx.x;
  int ch4 = idx & 2047;
  int chunk = idx >> 11;
  int b = ch4 >> 9;
  int c = (ch4 & 511) * 4;
  float g = gamma[c >> 7];
  float4 Sv = *(const float4*)(carry + (size_t)chunk * NCHAN + b * Cc + c);
  float S[4] = {Sv.x, Sv.y, Sv.z, Sv.w};
  const unsigned short* qb = qkv + ((size_t)(b * Tt + chunk * TCHUNK)) * NQKV + c;
  unsigned short* gp = gb + ((size_t)(b * Tt + chunk * TCHUNK)) * Cc + c;
#pragma unroll 4
  for (int t = 0; t < TCHUNK; t++) {
    const unsigned short* p = qb + (size_t)t * NQKV;
    uint2 qq = *(const uint2*)(p);
    uint2 kk = *(const uint2*)(p + Cc);
    uint2 vv = *(const uint2*)(p + 2 * Cc);
    uint2 gg = *(const uint2*)(gp + (size_t)t * Cc);
    float q0 = bf2f((unsigned short)(qq.x & 0xffff)), q1 = bf2f((unsigned short)(qq.x >> 16));
    float q2 = bf2f((unsigned short)(qq.y & 0xffff)), q3 = bf2f((unsigned short)(qq.y >> 16));
    float k0 = bf2f((unsigned short)(kk.x & 0xffff)), k1 = bf2f((unsigned short)(kk.x >> 16));
    float k2 = bf2f((unsigned short)(kk.y & 0xffff)), k3 = bf2f((unsigned short)(kk.y >> 16));
    float v0 = bf2f((unsigned short)(vv.x & 0xffff)), v1 = bf2f((unsigned short)(vv.x >> 16));
    float v2 = bf2f((unsigned short)(vv.y & 0xffff)), v3 = bf2f((unsigned short)(vv.y >> 16));
    float g0 = bf2f((unsigned short)(gg.x & 0xffff)), g1 = bf2f((unsigned short)(gg.x >> 16));
    float g2 = bf2f((unsigned short)(gg.y & 0xffff)), g3 = bf2f((unsigned short)(gg.y >> 16));
    S[0] = g * S[0] + k0 * v0;
    S[1] = g * S[1] + k1 * v1;
    S[2] = g * S[2] + k2 * v2;
    S[3] = g * S[3] + k3 * v3;
    unsigned short o0 = f2bf(g0 * S[0] * q0);
    unsigned short o1 = f2bf(g1 * S[1] * q1);
    unsigned short o2 = f2bf(g2 * S[2] * q2);
    unsigned short o3 = f2bf(g3 * S[3] * q3);
    *(uint2*)(gp + (size_t)t * Cc) =
        make_uint2((unsigned)o0 | ((unsigned)o1 << 16), (unsigned)o2 | ((unsigned)o3 << 16));
  }
}

// ---------------- LayerNorm over C=2048, in-place on fp32 ----------------
__global__ __launch_bounds__(256) void ln_kernel(float* __restrict__ y,
                                                 const float* __restrict__ w,
                                                 const float* __restrict__ b) {
  float* p = y + (size_t)blockIdx.x * Cc;
  int tid = threadIdx.x;
  float v[8];
  float s = 0.f, sq = 0.f;
#pragma unroll
  for (int i = 0; i < 8; i++) {
    v[i] = p[tid + i * 256];
    s += v[i];
    sq += v[i] * v[i];
  }
#pragma unroll
  for (int o = 32; o > 0; o >>= 1) { s += __shfl_down(s, o); sq += __shfl_down(sq, o); }
  __shared__ float ss[4], ssq[4];
  int wave = tid >> 6, lane = tid & 63;
  if (lane == 0) { ss[wave] = s; ssq[wave] = sq; }
  __syncthreads();
  s = ss[0] + ss[1] + ss[2] + ss[3];
  sq = ssq[0] + ssq[1] + ssq[2] + ssq[3];
  float mu = s * (1.f / (float)Cc);
  float var = fmaxf(sq * (1.f / (float)Cc) - mu * mu, 0.f);
  float rs = rsqrtf(var + 1e-5f);
#pragma unroll
  for (int i = 0; i < 8; i++) {
    int c = tid + i * 256;
    p[c] = (v[i] - mu) * rs * w[c] + b[c];
  }
}

extern "C" void kernel_launch(void* const* d_in, const int* in_sizes, int n_in,
                              void* d_out, int out_size, void* d_ws, size_t ws_size,
                              hipStream_t stream) {
  const float* x      = (const float*)d_in[0];
  const float* Wq     = (const float*)d_in[1];
  const float* Wk     = (const float*)d_in[2];
  const float* Wv     = (const float*)d_in[3];
  const float* Wo     = (const float*)d_in[4];
  const float* conv_w = (const float*)d_in[5];
  const float* conv_b = (const float*)d_in[6];
  const float* gate_w = (const float*)d_in[7];
  const float* gate_b = (const float*)d_in[8];
  const float* ln_w   = (const float*)d_in[9];
  const float* ln_b   = (const float*)d_in[10];
  const float* gamma  = (const float*)d_in[11];

  char* ws = (char*)d_ws;
  const size_t SZ_BTC = (size_t)BT * Cc * 2;     // 64 MB (bf16 [BT, Cc])
  const size_t SZ_W   = (size_t)Cc * Cc * 2;     // 8 MB per weight
  unsigned short* xb   = (unsigned short*)(ws);
  unsigned short* xcb  = (unsigned short*)(ws + SZ_BTC);
  unsigned short* wb   = (unsigned short*)(ws + 2 * SZ_BTC);            // wq|wk|wv|wo|wg
  unsigned short* qkvb = (unsigned short*)(ws + 2 * SZ_BTC + 5 * SZ_W); // [BT, 6144]
  unsigned short* gb   = (unsigned short*)(ws + 2 * SZ_BTC + 5 * SZ_W + 3 * SZ_BTC);
  float* carry         = (float*)(ws + 2 * SZ_BTC + 5 * SZ_W + 4 * SZ_BTC); // 1 MB

  unsigned short* wob = wb + 3 * (size_t)Cc * Cc;
  unsigned short* wgb = wb + 4 * (size_t)Cc * Cc;

  const int nW = Cc * Cc;
  cvt5_kernel<<<5 * nW / 1024, 256, 0, stream>>>(Wq, Wk, Wv, Wo, gate_w, wb);
  conv_kernel<<<(BT / 8) * (Cc / 4) / 256, 256, 0, stream>>>(x, conv_w, conv_b, xb, xcb);

  // fused q/k/v GEMM with l2norm epilogue on q,k
  dim3 gqkv(BT / 128, NQKV / 128);
  gemm_bt<3><<<gqkv, 256, 0, stream>>>(xb, wb, qkvb, nullptr, BT, NQKV, Cc);

  // gate GEMM
  dim3 ggrid(BT / 128, Cc / 128);
  gemm_bt<1><<<ggrid, 256, 0, stream>>>(xcb, wgb, gb, gate_b, BT, Cc, Cc);

  // decayed scan + gating (out written in-place over gb)
  scan_p1<<<(NCHUNK * NCHAN / 4) / 256, 256, 0, stream>>>(qkvb, gamma, carry);
  scan_p2<<<NCHAN / 256, 256, 0, stream>>>(carry, gamma);
  scan_p3<<<(NCHUNK * NCHAN / 4) / 256, 256, 0, stream>>>(qkvb, gb, gamma, carry);

  // y = out @ Wo^T  (fp32 into d_out), then LayerNorm in place
  gemm_bt<2><<<ggrid, 256, 0, stream>>>(gb, wob, d_out, nullptr, BT, Cc, Cc);
  ln_kernel<<<BT, 256, 0, stream>>>((float*)d_out, ln_w, ln_b);
}